// Round 15
// baseline (307.828 us; speedup 1.0000x reference)
//
#include <hip/hip_runtime.h>
#include <hip/hip_bf16.h>

typedef _Float16 f16;
typedef _Float16 f16x8 __attribute__((ext_vector_type(8)));
typedef _Float16 f16x4 __attribute__((ext_vector_type(4)));
typedef float f32x4 __attribute__((ext_vector_type(4)));
typedef float f32x16 __attribute__((ext_vector_type(16)));

#define MFMA1632(a, b, c) __builtin_amdgcn_mfma_f32_16x16x32_f16(a, b, c, 0, 0, 0)
#define MFMA3216(a, b, c) __builtin_amdgcn_mfma_f32_32x32x16_f16(a, b, c, 0, 0, 0)

static constexpr int S  = 4096;
static constexpr int NB = 4;    // batches

// ---------------------------------------------------------------------------
// Weight convert + transpose, all four weights in one launch.
// ---------------------------------------------------------------------------
__global__ void wconv4_kernel(const float* __restrict__ W0, const float* __restrict__ W1,
                              const float* __restrict__ W2, const float* __restrict__ W3,
                              f16* __restrict__ T0, f16* __restrict__ T1,
                              f16* __restrict__ T2, f16* __restrict__ T3) {
    int j = blockIdx.x >> 8;
    int k = blockIdx.x & 255;
    int n = threadIdx.x;
    const float* W = (j == 0) ? W0 : (j == 1) ? W1 : (j == 2) ? W2 : W3;
    f16*         T = (j == 0) ? T0 : (j == 1) ? T1 : (j == 2) ? T2 : T3;
    T[n * 256 + k] = (f16)W[k * 256 + n];
}

// ---------------------------------------------------------------------------
// Fused K + V + K-hat projection from `value` (unchanged, proven).
// ---------------------------------------------------------------------------
__global__ __launch_bounds__(512) void kvhproj_kernel(
    const float* __restrict__ Af,
    const f16* __restrict__ WkT, const f16* __restrict__ WvT,
    const f16* __restrict__ WrT,
    const float* __restrict__ bk, const float* __restrict__ bv,
    const float* __restrict__ br,
    f16* __restrict__ Hf, f16* __restrict__ VtF)
{
    __shared__ f16 KS[32][264];      // K tile, +16B row pad

    int mbase = blockIdx.x * 32;
    int tid = threadIdx.x;
    int w = tid >> 6, l = tid & 63;
    int lr = l & 15, lg = l >> 4;
    int path = w >> 2;               // 0: K->LDS, 1: V->global
    int nbase = (w & 3) * 64;
    const f16* Wt = path ? WvT : WkT;
    const float* bias = path ? bv : bk;

    f32x4 acc[2][4];
#pragma unroll
    for (int mf = 0; mf < 2; ++mf)
#pragma unroll
        for (int nf = 0; nf < 4; ++nf) acc[mf][nf] = f32x4{0.f, 0.f, 0.f, 0.f};

#pragma unroll
    for (int ks = 0; ks < 8; ++ks) {
        int kof = ks * 32 + lg * 8;
        f16x8 a[2], b[4];
#pragma unroll
        for (int mf = 0; mf < 2; ++mf) {
            int row = mbase + mf * 16 + lr;
            const float4* p = (const float4*)(Af + row * 256 + kof);
            float4 x0 = p[0], x1 = p[1];
            f16x8 t;
            t[0] = (f16)x0.x; t[1] = (f16)x0.y; t[2] = (f16)x0.z; t[3] = (f16)x0.w;
            t[4] = (f16)x1.x; t[5] = (f16)x1.y; t[6] = (f16)x1.z; t[7] = (f16)x1.w;
            a[mf] = t;
        }
#pragma unroll
        for (int nf = 0; nf < 4; ++nf) {
            int col = nbase + nf * 16 + lr;
            b[nf] = *(const f16x8*)(Wt + col * 256 + kof);
        }
#pragma unroll
        for (int mf = 0; mf < 2; ++mf)
#pragma unroll
            for (int nf = 0; nf < 4; ++nf)
                acc[mf][nf] = MFMA1632(a[mf], b[nf], acc[mf][nf]);
    }

#pragma unroll
    for (int mf = 0; mf < 2; ++mf) {
#pragma unroll
        for (int nf = 0; nf < 4; ++nf) {
            int col = nbase + nf * 16 + lr;
            float bv2 = bias[col];
            if (path == 0) {
#pragma unroll
                for (int r = 0; r < 4; ++r)
                    KS[mf * 16 + lg * 4 + r][col] = (f16)(acc[mf][nf][r] + bv2);
            } else {
                int bi = mbase >> 12;
                int s  = (mbase & (S - 1)) + mf * 16 + lg * 4;
                f16x4 v;
#pragma unroll
                for (int r = 0; r < 4; ++r) v[r] = (f16)(acc[mf][nf][r] + bv2);
                *(f16x4*)(VtF + ((bi * 256 + col) * S + s)) = v;
            }
        }
    }
    __syncthreads();

    // ---- Phase 2: Khat = cos(K @ Wr + br), all 8 waves, 32 cols each ----
    f32x4 acc2[2][2];
#pragma unroll
    for (int mf = 0; mf < 2; ++mf)
#pragma unroll
        for (int nf = 0; nf < 2; ++nf) acc2[mf][nf] = f32x4{0.f, 0.f, 0.f, 0.f};

#pragma unroll
    for (int ks = 0; ks < 8; ++ks) {
        int kof = ks * 32 + lg * 8;
        f16x8 a[2], b[2];
#pragma unroll
        for (int mf = 0; mf < 2; ++mf)
            a[mf] = *(const f16x8*)&KS[mf * 16 + lr][kof];
#pragma unroll
        for (int nf = 0; nf < 2; ++nf) {
            int col = w * 32 + nf * 16 + lr;
            b[nf] = *(const f16x8*)(WrT + col * 256 + kof);
        }
#pragma unroll
        for (int mf = 0; mf < 2; ++mf)
#pragma unroll
            for (int nf = 0; nf < 2; ++nf)
                acc2[mf][nf] = MFMA1632(a[mf], b[nf], acc2[mf][nf]);
    }

#pragma unroll
    for (int mf = 0; mf < 2; ++mf) {
#pragma unroll
        for (int nf = 0; nf < 2; ++nf) {
            int col = w * 32 + nf * 16 + lr;
            float bv2 = br[col];
#pragma unroll
            for (int r = 0; r < 4; ++r) {
                int row = mbase + mf * 16 + lg * 4 + r;
                Hf[row * 256 + col] = (f16)cosf(acc2[mf][nf][r] + bv2);
            }
        }
    }
}

// ---------------------------------------------------------------------------
// Flash attention, QBLK=32, KBLK=256, 512 blocks x 8 waves, 2+ blocks/CU.
//   Wave w: QK key-slice kt + w*32..+32 (S^T[32k x 32q], lane owns q=lm);
//           PV d-slice w*32..+32 (O[32q x 32d], oac = 16 regs).
//   K-hat and V rows are WAVE-EXCLUSIVE -> read DIRECT from global (L2-
//   resident per XCD, zero duplication); latency hidden by 4 waves/SIMD.
//   LDS: Q [32][256] (chunk^=row&31, read per-use -> no qf registers) +
//   P double-buffered [2][32][256] (chunk^=q&31) + aux  ~= 51 KB.
//   Softmax: per-lane state for q=lm, block-uniform mrun via flag protocol
//   (defer-max thr 8); epilogue denominator = plain 8-way sum (same mrun).
//   2 barriers/iter (flag publish, P visibility); P dbuf kills B_end.
// Grid: 512 blocks.  bid&7 -> XCD; batch b = (bid>>1)&3 pins to 2 XCDs.
// ---------------------------------------------------------------------------
__global__ __launch_bounds__(512, 4) void attn_kernel(
    const float* __restrict__ query, const f16* __restrict__ WqT,
    const float* __restrict__ bq,
    const f16* __restrict__ Hf, const f16* __restrict__ Vt,
    float* __restrict__ Out)
{
    __shared__ f16 QS[32 * 256];        // 16 KB, chunk ^= (row&31)
    __shared__ f16 PSh[2][32 * 256];    // 32 KB, chunk ^= (row&31)
    __shared__ float auxF[8][32];       // per-wave row max / lsum partials
    __shared__ float auxT[32];          // trigger corr per q
    __shared__ float auxC[32];          // epilogue 1/denominator per q
    __shared__ int flagLds;

    int bid = blockIdx.x;
    int b   = (bid >> 1) & 3;
    int qi  = ((bid >> 3) << 1) | (bid & 1);   // 0..127
    int qbase = qi * 32;

    int tid = threadIdx.x;
    int w  = tid >> 6, l = tid & 63;
    int lm = l & 31;
    int h  = l >> 5;

    const f16* Hbase = Hf + (size_t)b * S * 256;
    const f16* Vbase = Vt + (size_t)b * 256 * S;

    if (tid == 0) flagLds = 0;

    // ---- fused Q projection: 32 rows x 256 cols; wave w -> cols w*32..+32 ----
    {
        int lr = l & 15, lg = l >> 4;
        int nc = w * 32;
        const float* Abase = query + (size_t)(b * S + qbase) * 256;

        f32x4 acc[2][2];
#pragma unroll
        for (int mf = 0; mf < 2; ++mf)
#pragma unroll
            for (int nf = 0; nf < 2; ++nf) acc[mf][nf] = f32x4{0.f, 0.f, 0.f, 0.f};

#pragma unroll
        for (int ks = 0; ks < 8; ++ks) {
            int kof = ks * 32 + lg * 8;
            f16x8 a[2], bb[2];
#pragma unroll
            for (int mf = 0; mf < 2; ++mf) {
                const float4* p = (const float4*)(Abase + (size_t)(mf * 16 + lr) * 256 + kof);
                float4 x0 = p[0], x1 = p[1];
                f16x8 t;
                t[0] = (f16)x0.x; t[1] = (f16)x0.y; t[2] = (f16)x0.z; t[3] = (f16)x0.w;
                t[4] = (f16)x1.x; t[5] = (f16)x1.y; t[6] = (f16)x1.z; t[7] = (f16)x1.w;
                a[mf] = t;
            }
#pragma unroll
            for (int nf = 0; nf < 2; ++nf) {
                int col = nc + nf * 16 + lr;
                bb[nf] = *(const f16x8*)(WqT + col * 256 + kof);
            }
#pragma unroll
            for (int mf = 0; mf < 2; ++mf)
#pragma unroll
                for (int nf = 0; nf < 2; ++nf)
                    acc[mf][nf] = MFMA1632(a[mf], bb[nf], acc[mf][nf]);
        }
#pragma unroll
        for (int mf = 0; mf < 2; ++mf) {
#pragma unroll
            for (int nf = 0; nf < 2; ++nf) {
                int col = nc + nf * 16 + lr;
                float bv = bq[col];
#pragma unroll
                for (int r = 0; r < 4; ++r) {
                    int row = mf * 16 + lg * 4 + r;
                    QS[row * 256 + (((col >> 3) ^ row) * 8) + (col & 7)] =
                        (f16)(acc[mf][nf][r] + bv);
                }
            }
        }
    }
    __syncthreads();

    f32x16 oac;
#pragma unroll
    for (int i = 0; i < 16; ++i) oac[i] = 0.f;
    float mrun = -1e30f, lsum = 0.f;

    const int NT = S / 256;     // 16 key-tiles of 256
    for (int t = 0; t < NT; ++t) {
        int cur = t & 1;
        int kt = t * 256;

        // ---- QK: S^T[32k x 32q] = Khat_rows . Q  (K-hat DIRECT from global) ----
        f32x16 s0, s1;
#pragma unroll
        for (int i = 0; i < 16; ++i) { s0[i] = 0.f; s1[i] = 0.f; }
        {
            const f16* kb = Hbase + (size_t)(kt + w * 32 + lm) * 256 + h * 8;
            const f16* qb = QS + (size_t)lm * 256;
            __builtin_amdgcn_s_setprio(1);
#pragma unroll
            for (int s = 0; s < 16; s += 2) {
                f16x8 ka0 = *(const f16x8*)(kb + s * 16);
                f16x8 ka1 = *(const f16x8*)(kb + (s + 1) * 16);
                f16x8 qv0 = *(const f16x8*)(qb + (((2 * s + h) ^ lm) * 8));
                f16x8 qv1 = *(const f16x8*)(qb + (((2 * s + 2 + h) ^ lm) * 8));
                s0 = MFMA3216(ka0, qv0, s0);
                s1 = MFMA3216(ka1, qv1, s1);
            }
            __builtin_amdgcn_s_setprio(0);
        }
        f32x16 sc;
#pragma unroll
        for (int i = 0; i < 16; ++i) sc[i] = s0[i] + s1[i];

        // ---- defer-max trigger detect (block-uniform flag protocol) ----
        int need = 0;
#pragma unroll
        for (int i = 0; i < 16; ++i) need |= (sc[i] > mrun + 8.f) ? 1 : 0;
        if (__any(need)) { if (l == 0) flagLds = 1; }
        asm volatile("s_waitcnt lgkmcnt(0)" ::: "memory");
        __builtin_amdgcn_s_barrier();        // B1: flag visible

        if (flagLds) {                       // rare, block-uniform
            float mx = sc[0];
#pragma unroll
            for (int i = 1; i < 16; ++i) mx = fmaxf(mx, sc[i]);
            mx = fmaxf(mx, __shfl_xor(mx, 32));
            if (h == 0) auxF[w][lm] = mx;
            __syncthreads();
            float mnew = mrun;
#pragma unroll
            for (int w2 = 0; w2 < 8; ++w2) mnew = fmaxf(mnew, auxF[w2][lm]);
            float corr = __expf(mrun - mnew);
            lsum *= corr;
            if (w == 0 && h == 0) auxT[lm] = corr;
            mrun = mnew;
            if (tid == 0) flagLds = 0;
            __syncthreads();
#pragma unroll
            for (int i = 0; i < 16; ++i)
                oac[i] *= auxT[(i & 3) + 8 * (i >> 2) + 4 * h];
        }

        // ---- exp + P write into PSh[cur] (row q=lm, chunk (4w+b4)^lm) ----
        {
            f16* pw = PSh[cur] + (size_t)lm * 256;
#pragma unroll
            for (int b4 = 0; b4 < 4; ++b4) {
                float p0 = __expf(sc[b4 * 4 + 0] - mrun);
                float p1 = __expf(sc[b4 * 4 + 1] - mrun);
                float p2 = __expf(sc[b4 * 4 + 2] - mrun);
                float p3 = __expf(sc[b4 * 4 + 3] - mrun);
                lsum += (p0 + p1) + (p2 + p3);
                f16x4 pv;
                pv[0] = (f16)p0; pv[1] = (f16)p1; pv[2] = (f16)p2; pv[3] = (f16)p3;
                *(f16x4*)(pw + (((4 * w + b4) ^ lm) * 8) + 4 * h) = pv;
            }
        }

        asm volatile("s_waitcnt lgkmcnt(0)" ::: "memory");
        __builtin_amdgcn_s_barrier();        // B2: P[cur] visible

        // ---- PV: O[32q x 32d] += P . V^T  (V DIRECT from global, exclusive
        //      d-rows w*32+lm; P from LDS, A-operand) ----
        {
            const f16* pr = PSh[cur] + (size_t)lm * 256;
            const f16* vrow = Vbase + (size_t)(w * 32 + lm) * S + kt + h * 8;
            __builtin_amdgcn_s_setprio(1);
#pragma unroll
            for (int s = 0; s < 16; ++s) {
                f16x8 pa = *(const f16x8*)(pr + (((2 * s + h) ^ lm) * 8));
                f16x8 vv = *(const f16x8*)(vrow + s * 16);
                oac = MFMA3216(pa, vv, oac);
            }
            __builtin_amdgcn_s_setprio(0);
        }
        // no B_end: next iter writes PSh[cur^1]; B1/B2 of t+1 fence reuse of
        // PSh[cur] at t+2 (lgkmcnt(0) at B1 drains these PV reads).
    }

    // ---- epilogue: denominator = 8-way sum (mrun block-uniform) ----
    lsum += __shfl_xor(lsum, 32);
    if (h == 0) auxF[w][lm] = lsum;
    __syncthreads();
    if (w == 0 && h == 0) {
        float den = auxF[0][lm] + auxF[1][lm] + auxF[2][lm] + auxF[3][lm]
                  + auxF[4][lm] + auxF[5][lm] + auxF[6][lm] + auxF[7][lm];
        auxC[lm] = 1.0f / den;
    }
    __syncthreads();

    float* Ob = Out + (size_t)(b * S + qbase) * 256 + w * 32 + lm;
#pragma unroll
    for (int i = 0; i < 16; ++i) {
        int cr = (i & 3) + 8 * (i >> 2) + 4 * h;
        Ob[(size_t)cr * 256] = oac[i] * auxC[cr];
    }
}

// ---------------------------------------------------------------------------
extern "C" void kernel_launch(void* const* d_in, const int* in_sizes, int n_in,
                              void* d_out, int out_size, void* d_ws, size_t ws_size,
                              hipStream_t stream)
{
    const float* query = (const float*)d_in[0];
    const float* value = (const float*)d_in[1];
    const float* Wq    = (const float*)d_in[2];
    const float* bq    = (const float*)d_in[3];
    const float* Wk    = (const float*)d_in[4];
    const float* bk    = (const float*)d_in[5];
    const float* Wv    = (const float*)d_in[6];
    const float* bv    = (const float*)d_in[7];
    const float* Wr    = (const float*)d_in[8];
    const float* br    = (const float*)d_in[9];
    float* out = (float*)d_out;

    char* ws = (char*)d_ws;
    size_t off = 0;
    auto alloc = [&](size_t bytes) -> char* {
        char* p = ws + off;
        off += (bytes + 255) & ~(size_t)255;
        return p;
    };
    f16* WqT = (f16*)alloc((size_t)65536 * 2);
    f16* WkT = (f16*)alloc((size_t)65536 * 2);
    f16* WvT = (f16*)alloc((size_t)65536 * 2);
    f16* WrT = (f16*)alloc((size_t)65536 * 2);
    f16* Hf  = (f16*)alloc((size_t)NB * S * 256 * 2);
    f16* VtF = (f16*)alloc((size_t)NB * S * 256 * 2);
    (void)ws_size; (void)in_sizes; (void)n_in; (void)out_size;

    wconv4_kernel<<<1024, 256, 0, stream>>>(Wq, Wk, Wv, Wr, WqT, WkT, WvT, WrT);

    // K, V, and Khat = cos(K @ Wr + br), fused (no Kf round-trip)
    kvhproj_kernel<<<512, 512, 0, stream>>>(value, WkT, WvT, WrT, bk, bv, br, Hf, VtF);

    // flash attention: QBLK=32, direct-global K-hat/V, 2+ blocks/CU
    attn_kernel<<<512, 512, 0, stream>>>(query, WqT, bq, Hf, VtF, out);
}

// Round 16
// 148.994 us; speedup vs baseline: 2.0660x; 2.0660x over previous
//
#include <hip/hip_runtime.h>
#include <hip/hip_bf16.h>

typedef _Float16 f16;
typedef _Float16 f16x8 __attribute__((ext_vector_type(8)));
typedef _Float16 f16x4 __attribute__((ext_vector_type(4)));
typedef float f32x4 __attribute__((ext_vector_type(4)));
typedef float f32x16 __attribute__((ext_vector_type(16)));

#define MFMA1632(a, b, c) __builtin_amdgcn_mfma_f32_16x16x32_f16(a, b, c, 0, 0, 0)
#define MFMA3216(a, b, c) __builtin_amdgcn_mfma_f32_32x32x16_f16(a, b, c, 0, 0, 0)

// async global->LDS, 16B per lane; LDS dest = wave-uniform base + lane*16
#define GLL16(g, l)                                                        \
    __builtin_amdgcn_global_load_lds(                                      \
        (const __attribute__((address_space(1))) void*)(g),                \
        (__attribute__((address_space(3))) void*)(l), 16, 0, 0)

static constexpr int S  = 4096;
static constexpr int NB = 4;    // batches

// ---------------------------------------------------------------------------
// Weight convert + transpose, all four weights in one launch.
// ---------------------------------------------------------------------------
__global__ void wconv4_kernel(const float* __restrict__ W0, const float* __restrict__ W1,
                              const float* __restrict__ W2, const float* __restrict__ W3,
                              f16* __restrict__ T0, f16* __restrict__ T1,
                              f16* __restrict__ T2, f16* __restrict__ T3) {
    int j = blockIdx.x >> 8;
    int k = blockIdx.x & 255;
    int n = threadIdx.x;
    const float* W = (j == 0) ? W0 : (j == 1) ? W1 : (j == 2) ? W2 : W3;
    f16*         T = (j == 0) ? T0 : (j == 1) ? T1 : (j == 2) ? T2 : T3;
    T[n * 256 + k] = (f16)W[k * 256 + n];
}

// ---------------------------------------------------------------------------
// Fused K + V + K-hat projection from `value`.
//   NEW (r16): A-tile (32x256 fp32) is loaded + converted to f16 ONCE into
//   LDS by all 512 threads (was: each of 8 waves privately re-loading and
//   re-converting the same tile -> 8x redundant cvt VALU + L2 reads).
//   Phase 1: waves 0-3 K -> KS LDS; waves 4-7 V -> global transposed VtF.
//   Phase 2: all 8 waves Khat = cos(K @ Wr + br) -> Hf.
// ---------------------------------------------------------------------------
__global__ __launch_bounds__(512) void kvhproj_kernel(
    const float* __restrict__ Af,
    const f16* __restrict__ WkT, const f16* __restrict__ WvT,
    const f16* __restrict__ WrT,
    const float* __restrict__ bk, const float* __restrict__ bv,
    const float* __restrict__ br,
    f16* __restrict__ Hf, f16* __restrict__ VtF)
{
    __shared__ f16 AS[32][264];      // A tile (f16), +16B row pad
    __shared__ f16 KS[32][264];      // K tile, +16B row pad

    int mbase = blockIdx.x * 32;
    int tid = threadIdx.x;
    int w = tid >> 6, l = tid & 63;
    int lr = l & 15, lg = l >> 4;
    int path = w >> 2;               // 0: K->LDS, 1: V->global
    int nbase = (w & 3) * 64;
    const f16* Wt = path ? WvT : WkT;
    const float* bias = path ? bv : bk;

    // ---- stage A once: thread i -> row i>>4, cols (i&15)*16 .. +16 ----
    {
        int row = tid >> 4;
        int col = (tid & 15) * 16;
        const float4* p = (const float4*)(Af + (size_t)(mbase + row) * 256 + col);
        float4 x0 = p[0], x1 = p[1], x2 = p[2], x3 = p[3];
        f16x8 t0, t1;
        t0[0] = (f16)x0.x; t0[1] = (f16)x0.y; t0[2] = (f16)x0.z; t0[3] = (f16)x0.w;
        t0[4] = (f16)x1.x; t0[5] = (f16)x1.y; t0[6] = (f16)x1.z; t0[7] = (f16)x1.w;
        t1[0] = (f16)x2.x; t1[1] = (f16)x2.y; t1[2] = (f16)x2.z; t1[3] = (f16)x2.w;
        t1[4] = (f16)x3.x; t1[5] = (f16)x3.y; t1[6] = (f16)x3.z; t1[7] = (f16)x3.w;
        *(f16x8*)&AS[row][col]     = t0;
        *(f16x8*)&AS[row][col + 8] = t1;
    }
    __syncthreads();

    f32x4 acc[2][4];
#pragma unroll
    for (int mf = 0; mf < 2; ++mf)
#pragma unroll
        for (int nf = 0; nf < 4; ++nf) acc[mf][nf] = f32x4{0.f, 0.f, 0.f, 0.f};

#pragma unroll
    for (int ks = 0; ks < 8; ++ks) {
        int kof = ks * 32 + lg * 8;
        f16x8 a[2], b[4];
#pragma unroll
        for (int mf = 0; mf < 2; ++mf)
            a[mf] = *(const f16x8*)&AS[mf * 16 + lr][kof];
#pragma unroll
        for (int nf = 0; nf < 4; ++nf) {
            int col = nbase + nf * 16 + lr;
            b[nf] = *(const f16x8*)(Wt + col * 256 + kof);
        }
#pragma unroll
        for (int mf = 0; mf < 2; ++mf)
#pragma unroll
            for (int nf = 0; nf < 4; ++nf)
                acc[mf][nf] = MFMA1632(a[mf], b[nf], acc[mf][nf]);
    }

#pragma unroll
    for (int mf = 0; mf < 2; ++mf) {
#pragma unroll
        for (int nf = 0; nf < 4; ++nf) {
            int col = nbase + nf * 16 + lr;
            float bv2 = bias[col];
            if (path == 0) {
#pragma unroll
                for (int r = 0; r < 4; ++r)
                    KS[mf * 16 + lg * 4 + r][col] = (f16)(acc[mf][nf][r] + bv2);
            } else {
                int bi = mbase >> 12;
                int s  = (mbase & (S - 1)) + mf * 16 + lg * 4;
                f16x4 v;
#pragma unroll
                for (int r = 0; r < 4; ++r) v[r] = (f16)(acc[mf][nf][r] + bv2);
                *(f16x4*)(VtF + ((bi * 256 + col) * S + s)) = v;
            }
        }
    }
    __syncthreads();

    // ---- Phase 2: Khat = cos(K @ Wr + br), all 8 waves, 32 cols each ----
    f32x4 acc2[2][2];
#pragma unroll
    for (int mf = 0; mf < 2; ++mf)
#pragma unroll
        for (int nf = 0; nf < 2; ++nf) acc2[mf][nf] = f32x4{0.f, 0.f, 0.f, 0.f};

#pragma unroll
    for (int ks = 0; ks < 8; ++ks) {
        int kof = ks * 32 + lg * 8;
        f16x8 a[2], b[2];
#pragma unroll
        for (int mf = 0; mf < 2; ++mf)
            a[mf] = *(const f16x8*)&KS[mf * 16 + lr][kof];
#pragma unroll
        for (int nf = 0; nf < 2; ++nf) {
            int col = w * 32 + nf * 16 + lr;
            b[nf] = *(const f16x8*)(WrT + col * 256 + kof);
        }
#pragma unroll
        for (int mf = 0; mf < 2; ++mf)
#pragma unroll
            for (int nf = 0; nf < 2; ++nf)
                acc2[mf][nf] = MFMA1632(a[mf], b[nf], acc2[mf][nf]);
    }

#pragma unroll
    for (int mf = 0; mf < 2; ++mf) {
#pragma unroll
        for (int nf = 0; nf < 2; ++nf) {
            int col = w * 32 + nf * 16 + lr;
            float bv2 = br[col];
#pragma unroll
            for (int r = 0; r < 4; ++r) {
                int row = mbase + mf * 16 + lg * 4 + r;
                Hf[row * 256 + col] = (f16)cosf(acc2[mf][nf][r] + bv2);
            }
        }
    }
}

// ---------------------------------------------------------------------------
// Flash attention (round-13 structure, verified 127 us) — UNCHANGED.
//   Prologue: fused Q-proj via MFMA into VtS-as-scratch, qf registers.
//   Main loop: 32x32 MFMAs, KBLK=128, NT=32, counted-vmcnt barriers (T4),
//   gll staging, K-hat chunk^=(row&31), V chunk^=(d&15), P chunk^=(q&15).
// Grid: 256 blocks.  bid&7 -> XCD; batch b = (bid>>1)&3 pins to 2 XCDs.
// ---------------------------------------------------------------------------
__global__ __launch_bounds__(512, 2) void attn_kernel(
    const float* __restrict__ query, const f16* __restrict__ WqT,
    const float* __restrict__ bq,
    const f16* __restrict__ Hf, const f16* __restrict__ Vt,
    float* __restrict__ Out)
{
    __shared__ f16 KhS[128 * 256];      // 64 KB
    __shared__ f16 VtS[256 * 128];      // 64 KB (prologue: Q scratch [64][264])
    __shared__ f16 PSh[64 * 128];       // 16 KB
    __shared__ float auxF[2][4][32];    // per-(qh,kg) row max / lsum partials
    __shared__ float auxT[2][32];       // trigger corr
    __shared__ float auxC[2][32];       // epilogue 1/denominator
    __shared__ int flagLds;

    int bid = blockIdx.x;
    int b   = (bid >> 1) & 3;
    int qi  = ((bid >> 3) << 1) | (bid & 1);
    int qbase = qi * 64;

    int tid = threadIdx.x;
    int w  = tid >> 6, l = tid & 63;
    int qh = w >> 2;            // QK q-half
    int kg = w & 3;             // QK key-slice
    int lm = l & 31;
    int h  = l >> 5;

    const f16* Hbase = Hf + (size_t)b * S * 256;
    const f16* Vbase = Vt + (size_t)b * 256 * S;

    if (tid == 0) flagLds = 0;

    // ---- fused Q projection into VtS-as-scratch [64][264] ----
    f16 (*QS)[264] = (f16(*)[264])VtS;
    {
        int lr = l & 15, lg = l >> 4;
        int mh = w >> 2;                 // row-half (32 rows)
        int nc = (w & 3) * 64;           // col-slice
        const float* Abase = query + (size_t)(b * S + qbase + mh * 32) * 256;

        f32x4 acc[2][4];
#pragma unroll
        for (int mf = 0; mf < 2; ++mf)
#pragma unroll
            for (int nf = 0; nf < 4; ++nf) acc[mf][nf] = f32x4{0.f, 0.f, 0.f, 0.f};

#pragma unroll
        for (int ks = 0; ks < 8; ++ks) {
            int kof = ks * 32 + lg * 8;
            f16x8 a[2], bb[4];
#pragma unroll
            for (int mf = 0; mf < 2; ++mf) {
                const float4* p = (const float4*)(Abase + (size_t)(mf * 16 + lr) * 256 + kof);
                float4 x0 = p[0], x1 = p[1];
                f16x8 t;
                t[0] = (f16)x0.x; t[1] = (f16)x0.y; t[2] = (f16)x0.z; t[3] = (f16)x0.w;
                t[4] = (f16)x1.x; t[5] = (f16)x1.y; t[6] = (f16)x1.z; t[7] = (f16)x1.w;
                a[mf] = t;
            }
#pragma unroll
            for (int nf = 0; nf < 4; ++nf) {
                int col = nc + nf * 16 + lr;
                bb[nf] = *(const f16x8*)(WqT + col * 256 + kof);
            }
#pragma unroll
            for (int mf = 0; mf < 2; ++mf)
#pragma unroll
                for (int nf = 0; nf < 4; ++nf)
                    acc[mf][nf] = MFMA1632(a[mf], bb[nf], acc[mf][nf]);
        }
#pragma unroll
        for (int mf = 0; mf < 2; ++mf) {
#pragma unroll
            for (int nf = 0; nf < 4; ++nf) {
                int col = nc + nf * 16 + lr;
                float bv = bq[col];
#pragma unroll
                for (int r = 0; r < 4; ++r)
                    QS[mh * 32 + mf * 16 + lg * 4 + r][col] = (f16)(acc[mf][nf][r] + bv);
            }
        }
    }
    __syncthreads();

    // Q B-fragments: q-col = qbase + qh*32 + lm  (64 VGPR, resident)
    f16x8 qf[16];
    {
        const f16* qp = &QS[qh * 32 + lm][h * 8];
#pragma unroll
        for (int s = 0; s < 16; ++s) qf[s] = *(const f16x8*)(qp + s * 16);
    }
    __syncthreads();   // all qf reads done before staging overwrites scratch

    f32x16 oac0, oac1;
#pragma unroll
    for (int i = 0; i < 16; ++i) { oac0[i] = 0.f; oac1[i] = 0.f; }
    float mrun = -1e30f, lsum = 0.f;

    // ---- prologue: gll-stage K-hat[0] (all threads) and V[0] (wave-sliced)
#pragma unroll
    for (int i = 0; i < 8; ++i) {
        int c = i * 512 + tid;
        int row = c >> 5, ch = c & 31;
        GLL16(Hbase + (size_t)row * 256 + ((ch ^ (row & 31)) * 8),
              KhS + (size_t)(i * 4096 + w * 512));
    }
#pragma unroll
    for (int i = 0; i < 8; ++i) {
        int d  = w * 32 + i * 4 + (l >> 4);
        int cp = l & 15;
        GLL16(Vbase + (size_t)d * S + ((cp ^ (d & 15)) * 8),
              VtS + (size_t)(w * 4096 + i * 512));
    }
    __syncthreads();    // full drain -> tile 0 landed

    const int NT = S / 128;     // 32 key-tiles
    for (int t = 0; t < NT; ++t) {
        int kt = t * 128;

        // ---- QK: S^T = Khat_slice . Q  (A rows = keys, B cols = q) ----
        f32x16 s0, s1;
#pragma unroll
        for (int i = 0; i < 16; ++i) { s0[i] = 0.f; s1[i] = 0.f; }
        {
            const f16* kb = KhS + (size_t)(kg * 32 + lm) * 256;
            __builtin_amdgcn_s_setprio(1);
#pragma unroll
            for (int s = 0; s < 16; s += 2) {
                f16x8 ka0 = *(const f16x8*)(kb + ((2 * s + h) ^ lm) * 8);
                f16x8 ka1 = *(const f16x8*)(kb + ((2 * s + 2 + h) ^ lm) * 8);
                s0 = MFMA3216(ka0, qf[s], s0);
                s1 = MFMA3216(ka1, qf[s + 1], s1);
            }
            __builtin_amdgcn_s_setprio(0);
        }
        f32x16 sc;
#pragma unroll
        for (int i = 0; i < 16; ++i) sc[i] = s0[i] + s1[i];

        // ---- defer-max trigger detect (block-uniform flag protocol) ----
        int need = 0;
#pragma unroll
        for (int i = 0; i < 16; ++i) need |= (sc[i] > mrun + 8.f) ? 1 : 0;
        if (__any(need)) { if (l == 0) flagLds = 1; }
        __syncthreads();   // B1: flag visible; K-hat[t] reads done; V[t] landed

        // ---- gll-stage K-hat[t+1] (overwrite safe; lands by B_end) ----
        if (t + 1 < NT) {
#pragma unroll
            for (int i = 0; i < 8; ++i) {
                int c = i * 512 + tid;
                int row = c >> 5, ch = c & 31;
                GLL16(Hbase + (size_t)(kt + 128 + row) * 256 + ((ch ^ (row & 31)) * 8),
                      KhS + (size_t)(i * 4096 + w * 512));
            }
        }

        if (flagLds) {                   // rare, block-uniform
            float mx = sc[0];
#pragma unroll
            for (int i = 1; i < 16; ++i) mx = fmaxf(mx, sc[i]);
            mx = fmaxf(mx, __shfl_xor(mx, 32));
            if (l < 32) auxF[qh][kg][lm] = mx;
            __syncthreads();
            float mnew = fmaxf(fmaxf(auxF[qh][0][lm], auxF[qh][1][lm]),
                               fmaxf(auxF[qh][2][lm], auxF[qh][3][lm]));
            mnew = fmaxf(mrun, mnew);
            float corr = __expf(mrun - mnew);
            lsum *= corr;
            if (kg == 0 && l < 32) auxT[qh][lm] = corr;
            mrun = mnew;
            if (tid == 0) flagLds = 0;
            __syncthreads();
#pragma unroll
            for (int i = 0; i < 16; ++i) {
                int cr = (i & 3) + 8 * (i >> 2) + 4 * h;
                oac0[i] *= auxT[0][cr];
                oac1[i] *= auxT[1][cr];
            }
        }

        // ---- exp + P write (16-chunk rows, key q&15 -> conflict-free) ----
        {
            f16* pw = PSh + (size_t)(qh * 32 + lm) * 128;
            int key = lm & 15;
#pragma unroll
            for (int b4 = 0; b4 < 4; ++b4) {
                float p0 = __expf(sc[b4 * 4 + 0] - mrun);
                float p1 = __expf(sc[b4 * 4 + 1] - mrun);
                float p2 = __expf(sc[b4 * 4 + 2] - mrun);
                float p3 = __expf(sc[b4 * 4 + 3] - mrun);
                lsum += (p0 + p1) + (p2 + p3);
                f16x4 pv;
                pv[0] = (f16)p0; pv[1] = (f16)p1; pv[2] = (f16)p2; pv[3] = (f16)p3;
                *(f16x4*)(pw + ((4 * kg + b4) ^ key) * 8 + 4 * h) = pv;
            }
        }

        // B2: P visible to all waves; K-hat[t+1] glls NOT drained
        asm volatile("s_waitcnt lgkmcnt(0)" ::: "memory");
        __builtin_amdgcn_s_barrier();

        // ---- PV: O[64q x 32d] += P . V^T (A = P rows=q, B = V cols=d) ----
        {
            const f16* pb0 = PSh + (size_t)lm * 128;
            const f16* pb1 = PSh + (size_t)(32 + lm) * 128;
            const f16* vb  = VtS + (size_t)(w * 32 + lm) * 128;
            int kp = lm & 15;
            __builtin_amdgcn_s_setprio(1);
#pragma unroll
            for (int s = 0; s < 8; ++s) {
                int lc = 2 * s + h;
                f16x8 pa0 = *(const f16x8*)(pb0 + (lc ^ kp) * 8);
                f16x8 pa1 = *(const f16x8*)(pb1 + (lc ^ kp) * 8);
                f16x8 vv  = *(const f16x8*)(vb  + (lc ^ kp) * 8);
                oac0 = MFMA3216(pa0, vv, oac0);
                oac1 = MFMA3216(pa1, vv, oac1);
            }
            __builtin_amdgcn_s_setprio(0);
        }

        // ---- gll-stage V[t+1], wave-sliced (only rows this wave reads) ----
        if (t + 1 < NT) {
#pragma unroll
            for (int i = 0; i < 8; ++i) {
                int d  = w * 32 + i * 4 + (l >> 4);
                int cp = l & 15;
                GLL16(Vbase + (size_t)d * S + (kt + 128) + ((cp ^ (d & 15)) * 8),
                      VtS + (size_t)(w * 4096 + i * 512));
            }
        }

        // B_end: wait K-hat[t+1] (oldest 8) landed; V[t+1] (newest 8) in flight
        asm volatile("s_waitcnt vmcnt(8)" ::: "memory");
        __builtin_amdgcn_s_barrier();
    }

    // ---- epilogue: denominators across (kg,h) partials; write; no O merge ----
    lsum += __shfl_xor(lsum, 32);
    if (l < 32) auxF[qh][kg][lm] = lsum;
    __syncthreads();
    if (kg == 0 && l < 32) {
        float dsum = auxF[qh][0][lm] + auxF[qh][1][lm] +
                     auxF[qh][2][lm] + auxF[qh][3][lm];
        auxC[qh][lm] = 1.0f / dsum;
    }
    __syncthreads();

    float* Ob = Out + (size_t)(b * S + qbase) * 256 + w * 32 + lm;
#pragma unroll
    for (int i = 0; i < 16; ++i) {
        int cr = (i & 3) + 8 * (i >> 2) + 4 * h;
        Ob[(size_t)cr * 256]        = oac0[i] * auxC[0][cr];
        Ob[(size_t)(32 + cr) * 256] = oac1[i] * auxC[1][cr];
    }
}

// ---------------------------------------------------------------------------
extern "C" void kernel_launch(void* const* d_in, const int* in_sizes, int n_in,
                              void* d_out, int out_size, void* d_ws, size_t ws_size,
                              hipStream_t stream)
{
    const float* query = (const float*)d_in[0];
    const float* value = (const float*)d_in[1];
    const float* Wq    = (const float*)d_in[2];
    const float* bq    = (const float*)d_in[3];
    const float* Wk    = (const float*)d_in[4];
    const float* bk    = (const float*)d_in[5];
    const float* Wv    = (const float*)d_in[6];
    const float* bv    = (const float*)d_in[7];
    const float* Wr    = (const float*)d_in[8];
    const float* br    = (const float*)d_in[9];
    float* out = (float*)d_out;

    char* ws = (char*)d_ws;
    size_t off = 0;
    auto alloc = [&](size_t bytes) -> char* {
        char* p = ws + off;
        off += (bytes + 255) & ~(size_t)255;
        return p;
    };
    f16* WqT = (f16*)alloc((size_t)65536 * 2);
    f16* WkT = (f16*)alloc((size_t)65536 * 2);
    f16* WvT = (f16*)alloc((size_t)65536 * 2);
    f16* WrT = (f16*)alloc((size_t)65536 * 2);
    f16* Hf  = (f16*)alloc((size_t)NB * S * 256 * 2);
    f16* VtF = (f16*)alloc((size_t)NB * S * 256 * 2);
    (void)ws_size; (void)in_sizes; (void)n_in; (void)out_size;

    wconv4_kernel<<<1024, 256, 0, stream>>>(Wq, Wk, Wv, Wr, WqT, WkT, WvT, WrT);

    // K, V, and Khat = cos(K @ Wr + br), fused; A-tile staged once in LDS
    kvhproj_kernel<<<512, 512, 0, stream>>>(value, WkT, WvT, WrT, bk, bv, br, Hf, VtF);

    // flash attention with fused Q projection (r13, verified)
    attn_kernel<<<256, 512, 0, stream>>>(query, WqT, bq, Hf, VtF, out);
}